// Round 5
// baseline (225.335 us; speedup 1.0000x reference)
//
#include <hip/hip_runtime.h>

// PatchEmbedding2 on MI355X — round 12.
// r11 post-mortem: top-5 all harness fillBuffer (~59us x2, fixed floor);
// non-gemm constant ~168us across r7-r11 => gemm ~54-57. Phase-split gave
// only ~3us: residual overhead = 4 barriers + 2 lgkm drains per K-tile, all
// waves of the ONLY block/CU stall together 192x.
// Fix (sync-structure only, geometry identical): move lgkmcnt(0) BEFORE the
// pre-MFMA barrier. Then each wave's ds_reads COMPLETE before it arrives at
// the barrier; any gll write to buf (t-1)%3 is issued only after that
// barrier's release (3-buf stage-ahead-2 => STG targets (t+2)%3==(t-1)%3),
// so the WAR guard holds and the post-MFMA barrier+drain is DELETED:
// 96 barriers instead of 192, MFMA cluster runs wait-free after the barrier.
// Also drop sched_barrier(0) (ds_reads are compiler-visible; let it
// interleave MFMA with next phase's ds_read/gll issue).
// vmcnt ledger unchanged and re-verified: VM5 once/tile at phase1 pre-barrier
// (own 10 outstanding -> waits tile t+1's 5 landed); epilogue VM0 at tile 46.
// prep/gather: unchanged (r3/r4-verified).

typedef __attribute__((ext_vector_type(8))) short bf16x8;
typedef __attribute__((ext_vector_type(4))) float f32x4;

#define K_DIM 3072
#define N_DIM 768
#define BM 192
#define BN 128

__device__ __forceinline__ unsigned short f2bf(float f) {
  unsigned int u = __float_as_uint(f);
  u += 0x7fffu + ((u >> 16) & 1u);   // RNE
  return (unsigned short)(u >> 16);
}

__device__ __forceinline__ void gload16(const void* g, void* l) {
  __builtin_amdgcn_global_load_lds(
      (const __attribute__((address_space(1))) void*)g,
      (__attribute__((address_space(3))) void*)l, 16, 0, 0);
}

// ---------------- prep: wconv (row-major) + layout ----------------
__global__ __launch_bounds__(1024)
void prep_kernel(const float* __restrict__ W, unsigned short* __restrict__ Wb, int w4,
                 const float* __restrict__ iw, int P,
                 int* __restrict__ tokBase, int* __restrict__ tokMask, int NB_W) {
  int bid = blockIdx.x;
  int tid = threadIdx.x;
  if (bid < NB_W) {
    int idx = bid * 1024 + tid;
    if (idx < w4) {
      float4 f = *(const float4*)(W + (size_t)idx * 4);
      ushort4 o;
      o.x = f2bf(f.x); o.y = f2bf(f.y); o.z = f2bf(f.z); o.w = f2bf(f.w);
      *(ushort4*)(Wb + (size_t)idx * 4) = o;
    }
    return;
  }
  // ---- layout (single block, r2-verified) ----
  __shared__ double s_wsum[16];
  __shared__ double s_avg;
  __shared__ int s_cnt[1024];
  float v = (tid < P) ? iw[tid] : 0.0f;
  double d = (double)v;
#pragma unroll
  for (int off = 32; off > 0; off >>= 1) d += __shfl_down(d, off, 64);
  if ((tid & 63) == 0) s_wsum[tid >> 6] = d;
  __syncthreads();
  if (tid == 0) {
    double s = 0.0;
    for (int i = 0; i < 16; ++i) s += s_wsum[i];
    s_avg = s / (double)P;
  }
  __syncthreads();
  int cnt = 0, sz = 32;
  if (tid < P) {
    double val = 32.0 * pow(s_avg / (double)v, 0.05);
    if (val > 32.0) val = 32.0;
    sz = (val >= 24.0) ? 32 : (val >= 12.0) ? 16 : (val >= 6.0) ? 8 : 4;
    cnt = (sz < 32) ? (32 / sz) : 1;
  }
  s_cnt[tid] = cnt;
  __syncthreads();
  for (int dl = 1; dl < 1024; dl <<= 1) {
    int add = (tid >= dl) ? s_cnt[tid - dl] : 0;
    __syncthreads();
    s_cnt[tid] += add;
    __syncthreads();
  }
  if (tid < P) {
    int off = s_cnt[tid] - cnt;
    int ini_col = (tid * 32) & 1023;
    int ini_row = (tid * 32 * 32) >> 10;
    if (sz == 32) {
      tokBase[off] = ini_row * 1024 + ini_col;
      tokMask[off] = 31;
    } else {
      int ns = 32 / sz;
      for (int j = 0; j < ns; ++j) {
        int r = ini_row + (j * sz) / ns;
        int c = ini_col + ((j * sz) & 31);
        tokBase[off + j] = r * 1024 + c;
        tokMask[off + j] = sz - 1;
      }
    }
  }
}

// ---------------- gather: row-major Ab, one block per A row (r3/r4-verified) ---
__global__ __launch_bounds__(256)
void gather_kernel(const float* __restrict__ x,
                   const int* __restrict__ tokBase,
                   const int* __restrict__ tokMask,
                   unsigned short* __restrict__ Ab) {
  int t = blockIdx.x;
  int b = blockIdx.y;
  int T = gridDim.x;
  int m = b * T + t;
  int base = tokBase[t];
  int mask = tokMask[t];
  int sh = __popc(mask);
  const float* xb = x + (size_t)b * 3145728 + (size_t)base;
  unsigned short* arow = Ab + (size_t)m * K_DIM;
#pragma unroll
  for (int it = 0; it < 3; ++it) {
    int g = it * 256 + threadIdx.x;
    int p = g * 4;
    int c = p >> 10;
    int f = p & 1023;
    int h = (f >> sh) & mask;
    int w = f & mask;
    float4 fv = *(const float4*)(xb + (size_t)c * 1048576 + h * 1024 + w);
    ushort4 o;
    o.x = f2bf(fv.x); o.y = f2bf(fv.y); o.z = f2bf(fv.z); o.w = f2bf(fv.w);
    *(ushort4*)(arow + p) = o;
  }
}

// -- gemm: 192x128 x BK64, 8 waves, 3-buf depth-2, 1 barrier/phase + setprio --
__global__ __launch_bounds__(512)
void gemm_kernel(const unsigned short* __restrict__ A, const unsigned short* __restrict__ Wb,
                 const float* __restrict__ bias, float* __restrict__ out, int Mtot) {
  // per buf: A 192x64 (24 KB) shorts [0,12288), B 128x64 (16 KB) [12288,20480).
  // row = 128 B = 8 chunks of 16 B; chunk c of row r stored at slot c^(r&7)
  // (swizzle applied in GLOBAL src addr; gll LDS dst is linear lane*16).
  __shared__ unsigned short lds[3][20480];   // 120 KB
  int tid = threadIdx.x;
  int lane = tid & 63;
  int wave = tid >> 6;                       // 0..7
  int wrM = wave >> 1, wrN = wave & 1;       // wave tile 48x64 at (wrM*48, wrN*64)

  // bijective XCD-chunked swizzle (m204), 252 blocks.
  int lin = blockIdx.x;
  int nwg = gridDim.x;                       // 252
  int q8 = nwg >> 3, r8 = nwg & 7;           // 31, 4
  int xcd = lin & 7, slot = lin >> 3;
  int wg = (xcd < r8) ? xcd * (q8 + 1) + slot
                      : r8 * (q8 + 1) + (xcd - r8) * q8 + slot;
  int mBase = (wg / 6) * BM;
  int nBase = (wg % 6) * BN;

  f32x4 acc[3][4] = {};

  // staging: uniform 5 gll/wave/tile. A: rows wave*24 + inst*8 + lrow (3 insts)
  // B: rows wave*16 + inst*8 + lrow (2 insts). 24,16,48,64 all ≡0 mod 8 so
  // row&7 == lane>>3 == lrow always; source chunk pre-swizzled (lane&7)^lrow.
  int lrow = lane >> 3;
  int schunk = (lane & 7) ^ lrow;
  const unsigned short* Ag = A + (size_t)(mBase + wave * 24 + lrow) * K_DIM + schunk * 8;
  const unsigned short* Bg = Wb + (size_t)(nBase + wave * 16 + lrow) * K_DIM + schunk * 8;
  unsigned short* Adst0 = &lds[0][(wave * 24) * 64] + lane * 8;           // +inst*512
  unsigned short* Bdst0 = &lds[0][12288 + (wave * 16) * 64] + lane * 8;   // +inst*512

#define STAGE_A(BUF, KOFF)                                                  \
    _Pragma("unroll")                                                       \
    for (int inst = 0; inst < 3; ++inst)                                    \
      gload16(Ag + (size_t)(inst * 8) * K_DIM + (KOFF),                     \
              Adst0 + (size_t)(BUF) * 20480 + inst * 512);

#define STAGE_B(BUF, KOFF)                                                  \
    _Pragma("unroll")                                                       \
    for (int inst = 0; inst < 2; ++inst)                                    \
      gload16(Bg + (size_t)(inst * 8) * K_DIM + (KOFF),                     \
              Bdst0 + (size_t)(BUF) * 20480 + inst * 512);

  int rr = lane & 15, q = lane >> 4;
  int r7 = rr & 7;

  // one phase: {ds_read frags; issue stage share; [vmcnt]; lgkmcnt(0);
  // barrier; prio-wrapped 12 MFMA}. lgkm BEFORE barrier => every wave's
  // reads are COMPLETE at barrier arrival, so a later gll write to the
  // stage target buf (issued only post-release) can never clobber an
  // in-flight read — the post-MFMA barrier of r11 is thereby removed.
#define PH(BUF, KH, STG, WAITC)                                             \
  {                                                                         \
    bf16x8 aF[3], bF[4];                                                    \
    _Pragma("unroll")                                                       \
    for (int i = 0; i < 3; ++i)                                             \
      aF[i] = *(const bf16x8*)&lds[BUF][(wrM * 48 + i * 16 + rr) * 64 +     \
                                        (((KH) * 4 + q) ^ r7) * 8];         \
    _Pragma("unroll")                                                       \
    for (int j = 0; j < 4; ++j)                                             \
      bF[j] = *(const bf16x8*)&lds[BUF][12288 +                             \
                                        (wrN * 64 + j * 16 + rr) * 64 +     \
                                        (((KH) * 4 + q) ^ r7) * 8];         \
    STG                                                                     \
    WAITC                                                                   \
    asm volatile("s_waitcnt lgkmcnt(0)" ::: "memory");                      \
    __builtin_amdgcn_s_barrier();                                           \
    __builtin_amdgcn_s_setprio(1);                                          \
    _Pragma("unroll")                                                       \
    for (int i = 0; i < 3; ++i)                                             \
      _Pragma("unroll")                                                     \
      for (int j = 0; j < 4; ++j)                                           \
        acc[i][j] = __builtin_amdgcn_mfma_f32_16x16x32_bf16(aF[i], bF[j],   \
                                                            acc[i][j], 0, 0, 0); \
    __builtin_amdgcn_s_setprio(0);                                          \
  }

#define VM5 asm volatile("s_waitcnt vmcnt(5)" ::: "memory");
#define VM0 asm volatile("s_waitcnt vmcnt(0)" ::: "memory");
#define NOP

  // iter t (buf t%3): phase0 stages A of tile t+2 into buf (t+2)%3==(t-1)%3,
  // phase1 stages B of t+2 then VM5 => tile t+1's 5 landed pre-barrier.
#define ITER(BUF, SBUF, KOFF)                                               \
  PH(BUF, 0, STAGE_A(SBUF, KOFF), NOP)                                      \
  PH(BUF, 1, STAGE_B(SBUF, KOFF), VM5)

  // prologue: stage tiles 0,1; wait tile 0 landed (10 outstanding -> vmcnt(5))
  STAGE_A(0, 0) STAGE_B(0, 0)
  STAGE_A(1, 64) STAGE_B(1, 64)
  VM5
  __builtin_amdgcn_s_barrier();

  for (int g = 0; g < 15; ++g) {             // tiles 0..44
    int k = g * 192;
    ITER(0, 2, k + 128)
    ITER(1, 0, k + 192)
    ITER(2, 1, k + 256)
  }
  // tile 45 (buf0): stages tile 47 into buf2
  ITER(0, 2, 3008)
  // tile 46 (buf1): nothing to stage; VM0 pre-barrier => tile 47 landed
  PH(1, 0, NOP, NOP)
  PH(1, 1, NOP, VM0)
  // tile 47 (buf2): drained
  PH(2, 0, NOP, NOP)
  PH(2, 1, NOP, NOP)
#undef ITER
#undef PH
#undef STAGE_A
#undef STAGE_B
#undef VM5
#undef VM0
#undef NOP

  // epilogue: C/D layout col=lane&15, row=(lane>>4)*4+reg (r2-verified)
#pragma unroll
  for (int j = 0; j < 4; ++j) {
    int n = nBase + wrN * 64 + j * 16 + rr;
    float bv = bias[n];
#pragma unroll
    for (int i = 0; i < 3; ++i) {
      int mrow = mBase + wrM * 48 + i * 16 + q * 4;
#pragma unroll
      for (int r2 = 0; r2 < 4; ++r2) {
        int m = mrow + r2;
        if (m < Mtot) out[(size_t)m * N_DIM + n] = acc[i][j][r2] + bv;
      }
    }
  }
}

extern "C" void kernel_launch(void* const* d_in, const int* in_sizes, int n_in,
                              void* d_out, int out_size, void* d_ws, size_t ws_size,
                              hipStream_t stream) {
  const float* x  = (const float*)d_in[0];
  const float* iw = (const float*)d_in[1];
  const float* W  = (const float*)d_in[2];
  const float* b  = (const float*)d_in[3];
  int P = in_sizes[1];                        // 992
  int B = in_sizes[0] / (3 * 1024 * 1024);    // 8
  int E = in_sizes[3];                        // 768
  int T = out_size / (B * E);                 // 995
  int Mtot = B * T;                           // 7960
  int mTiles = (Mtot + BM - 1) / BM;          // 42 (42*192 = 8064)

  char* ws = (char*)d_ws;
  int* tokBase = (int*)ws;                              // 32 KB
  int* tokMask = (int*)(ws + 32768);                    // 32 KB
  unsigned short* Wb = (unsigned short*)(ws + 65536);   // 4.72 MB row-major
  unsigned short* Ab = (unsigned short*)(ws + 65536 + (size_t)E * K_DIM * 2);

  int w4 = E * K_DIM / 4;                     // 589824
  int NB_W = (w4 + 1023) / 1024;              // 576
  prep_kernel<<<NB_W + 1, 1024, 0, stream>>>(W, Wb, w4, iw, P, tokBase, tokMask, NB_W);

  dim3 gGrid(T, B);
  gather_kernel<<<gGrid, 256, 0, stream>>>(x, tokBase, tokMask, Ab);

  // pad rows [Mtot, 8064) of Ab are never written; garbage affects only
  // output rows >= Mtot, guarded in the epilogue (matmul rows independent).

  dim3 grid((N_DIM / BN) * mTiles);           // 6*42 = 252 blocks, 1D for swizzle
  gemm_kernel<<<grid, 512, 0, stream>>>(Ab, Wb, b, (float*)d_out, Mtot);
}